// Round 4
// baseline (439.711 us; speedup 1.0000x reference)
//
#include <hip/hip_runtime.h>

#define B_ 8
#define T_ 4096
#define C_ 128
#define HS_ 64

typedef _Float16 f16;
typedef _Float16 f16x8 __attribute__((ext_vector_type(8)));
typedef _Float16 f16x4 __attribute__((ext_vector_type(4)));
typedef float f32x4 __attribute__((ext_vector_type(4)));

#define MFMA32(a, b, c) __builtin_amdgcn_mfma_f32_16x16x32_f16(a, b, c, 0, 0, 0)
#define MFMA16(a, b, c) __builtin_amdgcn_mfma_f32_16x16x16f16(a, b, c, 0, 0, 0)

// ---------------------------------------------------------------------------
// Prep: WT[j][c] f16, j in [0,192): 0-63 Wq (scaled by 1/sqrt(C)), 64-127 Wk,
// 128-191 Wv.  WT row-major [192][128].
// ---------------------------------------------------------------------------
__global__ void k_wprep(const float* __restrict__ Wq, const float* __restrict__ Wk,
                        const float* __restrict__ Wv, f16* __restrict__ WT) {
    int idx = blockIdx.x * 256 + threadIdx.x;
    if (idx >= 192 * C_) return;
    int j = idx >> 7, c = idx & 127;
    const float* W = (j < 64) ? Wq : (j < 128 ? Wk : Wv);
    float v = W[c * HS_ + (j & 63)];
    if (j < 64) v *= 0.08838834764831845f;     // 1/sqrt(128), folded into q
    WT[idx] = (f16)v;
}

// ---------------------------------------------------------------------------
// QKV projection + RoPE.  OUT^T = WT · x^T via 16x16x32 MFMA.
// C/D: lane holds rows j = jt*16 + g*4 + r (r=0..3), col t = t0 + (lane&15).
// RoPE pairs (2i,2i+1) are regs (0,1) and (2,3) of the same lane.
// Stores: Q,K as [b][t][64] f16 (packed 4 = 8B); V transposed VT[b][64][T].
// ---------------------------------------------------------------------------
__global__ __launch_bounds__(256) void k_qkv(const float* __restrict__ x,
        const f16* __restrict__ WT, const float* __restrict__ fcos,
        const float* __restrict__ fsin, f16* __restrict__ Q,
        f16* __restrict__ K, f16* __restrict__ VT) {
    const int b = blockIdx.y;
    const int w = threadIdx.x >> 6, lane = threadIdx.x & 63;
    const int col = lane & 15, g = lane >> 4;
    const int t = blockIdx.x * 64 + w * 16 + col;

    f16x8 bx[4];
    const float* xrow = x + ((size_t)(b * T_ + t)) * C_;
#pragma unroll
    for (int cc = 0; cc < 4; ++cc) {
        float4 x0 = *(const float4*)(xrow + cc * 32 + g * 8);
        float4 x1 = *(const float4*)(xrow + cc * 32 + g * 8 + 4);
        f16x8 v;
        v[0] = (f16)x0.x; v[1] = (f16)x0.y; v[2] = (f16)x0.z; v[3] = (f16)x0.w;
        v[4] = (f16)x1.x; v[5] = (f16)x1.y; v[6] = (f16)x1.z; v[7] = (f16)x1.w;
        bx[cc] = v;
    }

#pragma unroll
    for (int jt = 0; jt < 12; ++jt) {
        f32x4 acc = {0.f, 0.f, 0.f, 0.f};
#pragma unroll
        for (int cc = 0; cc < 4; ++cc) {
            f16x8 aw = *(const f16x8*)(WT + (size_t)(jt * 16 + col) * C_ + cc * 32 + g * 8);
            acc = MFMA32(aw, bx[cc], acc);
        }
        if (jt < 8) {
            const int hbase = (jt & 3) * 16 + g * 4;   // even head-dim base
            const int i0 = hbase >> 1;
            float c0 = fcos[t * 32 + i0],     s0 = fsin[t * 32 + i0];
            float c1 = fcos[t * 32 + i0 + 1], s1 = fsin[t * 32 + i0 + 1];
            float o0 = acc[0] * c0 - acc[1] * s0;
            float o1 = acc[0] * s0 + acc[1] * c0;
            float o2 = acc[2] * c1 - acc[3] * s1;
            float o3 = acc[2] * s1 + acc[3] * c1;
            f16x4 st; st[0] = (f16)o0; st[1] = (f16)o1; st[2] = (f16)o2; st[3] = (f16)o3;
            f16* dst = (jt < 4 ? Q : K);
            *(f16x4*)(dst + ((size_t)(b * T_ + t)) * HS_ + hbase) = st;
        } else {
            const int dbase = (jt - 8) * 16 + g * 4;
#pragma unroll
            for (int r = 0; r < 4; ++r)
                VT[((size_t)(b * HS_ + dbase + r)) * T_ + t] = (f16)acc[r];
        }
    }
}

// ---------------------------------------------------------------------------
// Flash attention. One wave = 16 q-rows; block = 4 waves = 64 q-rows.
// S^T = K·Q^T (16x16x32); softmax over kv lives in-lane (4 regs) + shfl 16/32.
// P^T (= S^T C/D layout) feeds 16x16x16 PV directly: O^T = V^T · P^T.
// O^T col = q = lane&15 matches lane-local m/lsum. No LDS, no syncthreads.
// Output is FLOAT32 (reference output dtype).
// ---------------------------------------------------------------------------
__global__ __launch_bounds__(256) void k_attn(const f16* __restrict__ Q,
        const f16* __restrict__ K, const f16* __restrict__ VT,
        const int* __restrict__ msk, float* __restrict__ out) {
    const int b = blockIdx.y;
    const int tq = (int)gridDim.x - 1 - (int)blockIdx.x;   // big tiles launch first
    const int w = threadIdx.x >> 6, lane = threadIdx.x & 63;
    const int col = lane & 15, g = lane >> 4;
    const int q0 = tq * 64 + w * 16;
    const int qc = q0 + col;

    const f16* qrow = Q + ((size_t)(b * T_ + qc)) * HS_;
    f16x8 bq0 = *(const f16x8*)(qrow + g * 8);
    f16x8 bq1 = *(const f16x8*)(qrow + 32 + g * 8);

    float m = -3.0e38f, lsum = 0.f;
    f32x4 o0 = {0,0,0,0}, o1 = {0,0,0,0}, o2 = {0,0,0,0}, o3 = {0,0,0,0};
    const int ntFull = tq * 4 + w;                 // it == ntFull is the diagonal
    const int* mrow = msk + b * T_;
    const f16* vb = VT + (size_t)b * HS_ * T_;

    for (int it = 0; it <= ntFull; ++it) {
        const int kv0 = it * 16;
        const f16* krow = K + ((size_t)(b * T_ + kv0 + col)) * HS_;
        f16x8 ak0 = *(const f16x8*)(krow + g * 8);
        f16x8 ak1 = *(const f16x8*)(krow + 32 + g * 8);
        f32x4 s = {0.f, 0.f, 0.f, 0.f};
        s = MFMA32(ak0, bq0, s);
        s = MFMA32(ak1, bq1, s);

        const int4 mk = *(const int4*)(mrow + kv0 + g * 4);
        const int kbase = kv0 + g * 4;
        if (it == ntFull) {
            s.x = (mk.x != 0 && kbase + 0 <= qc) ? s.x : -1e30f;
            s.y = (mk.y != 0 && kbase + 1 <= qc) ? s.y : -1e30f;
            s.z = (mk.z != 0 && kbase + 2 <= qc) ? s.z : -1e30f;
            s.w = (mk.w != 0 && kbase + 3 <= qc) ? s.w : -1e30f;
        } else {
            s.x = (mk.x != 0) ? s.x : -1e30f;
            s.y = (mk.y != 0) ? s.y : -1e30f;
            s.z = (mk.z != 0) ? s.z : -1e30f;
            s.w = (mk.w != 0) ? s.w : -1e30f;
        }

        float tm = fmaxf(fmaxf(s.x, s.y), fmaxf(s.z, s.w));
        tm = fmaxf(tm, __shfl_xor(tm, 16));
        tm = fmaxf(tm, __shfl_xor(tm, 32));
        float mn = fmaxf(m, tm);
        float sc = __expf(m - mn);
        float p0 = __expf(s.x - mn), p1 = __expf(s.y - mn);
        float p2 = __expf(s.z - mn), p3 = __expf(s.w - mn);
        float ts = p0 + p1 + p2 + p3;
        ts += __shfl_xor(ts, 16);
        ts += __shfl_xor(ts, 32);
        lsum = lsum * sc + ts;
        m = mn;

        f16x4 pf; pf[0] = (f16)p0; pf[1] = (f16)p1; pf[2] = (f16)p2; pf[3] = (f16)p3;
        const f16* vbase = vb + kv0 + g * 4;
        f16x4 av0 = *(const f16x4*)(vbase + (size_t)(col)      * T_);
        f16x4 av1 = *(const f16x4*)(vbase + (size_t)(col + 16) * T_);
        f16x4 av2 = *(const f16x4*)(vbase + (size_t)(col + 32) * T_);
        f16x4 av3 = *(const f16x4*)(vbase + (size_t)(col + 48) * T_);
        o0 *= sc; o1 *= sc; o2 *= sc; o3 *= sc;
        o0 = MFMA16(av0, pf, o0);
        o1 = MFMA16(av1, pf, o1);
        o2 = MFMA16(av2, pf, o2);
        o3 = MFMA16(av3, pf, o3);
    }

    const float inv = 1.0f / lsum;
    float* orow = out + ((size_t)(b * T_ + qc)) * HS_;
    float4 u;
    u.x = o0.x * inv; u.y = o0.y * inv; u.z = o0.z * inv; u.w = o0.w * inv;
    *(float4*)(orow + 0  + g * 4) = u;
    u.x = o1.x * inv; u.y = o1.y * inv; u.z = o1.z * inv; u.w = o1.w * inv;
    *(float4*)(orow + 16 + g * 4) = u;
    u.x = o2.x * inv; u.y = o2.y * inv; u.z = o2.z * inv; u.w = o2.w * inv;
    *(float4*)(orow + 32 + g * 4) = u;
    u.x = o3.x * inv; u.y = o3.y * inv; u.z = o3.z * inv; u.w = o3.w * inv;
    *(float4*)(orow + 48 + g * 4) = u;
}

// ---------------------------------------------------------------------------
extern "C" void kernel_launch(void* const* d_in, const int* in_sizes, int n_in,
                              void* d_out, int out_size, void* d_ws, size_t ws_size,
                              hipStream_t stream) {
    const float* x    = (const float*)d_in[0];
    const float* Wq   = (const float*)d_in[1];
    const float* Wk   = (const float*)d_in[2];
    const float* Wv   = (const float*)d_in[3];
    const float* fcos = (const float*)d_in[4];
    const float* fsin = (const float*)d_in[5];
    const int*   msk  = (const int*)d_in[6];

    char* ws = (char*)d_ws;
    const size_t qkv_bytes = (size_t)B_ * T_ * HS_ * sizeof(f16);   // 4 MB each
    f16* WT = (f16*)ws;                                  // 48 KB
    f16* Q  = (f16*)(ws + (1 << 16));
    f16* K  = (f16*)(ws + (1 << 16) + qkv_bytes);
    f16* VT = (f16*)(ws + (1 << 16) + 2 * qkv_bytes);

    k_wprep<<<96, 256, 0, stream>>>(Wq, Wk, Wv, WT);
    dim3 g1(T_ / 64, B_);
    k_qkv<<<g1, 256, 0, stream>>>(x, WT, fcos, fsin, Q, K, VT);
    dim3 g2(T_ / 64, B_);
    k_attn<<<g2, 256, 0, stream>>>(Q, K, VT, msk, (float*)d_out);
}